// Round 10
// baseline (2550.940 us; speedup 1.0000x reference)
//
#include <hip/hip_runtime.h>

#define Hd 128
#define Tn 1024
#define Dn 5
#define Ln 16
#define Bn 512
// Quarter-gapped hidden layout: quarter q (32 floats) lives at float offset
// 36*q. The 4 per-wave broadcast addresses (kq=0..3) then land on banks
// {4k,4k+4,4k+8,4k+12} mod 32 -> four DISJOINT bank quads, conflict-free.
#define QP 36
#define HP4 144
#define GF(f) ((f) + (((f) >> 5) << 2))            // linear h index -> gapped
#define CF(q) (QP * ((q) >> 3) + 4 * ((q) & 7))    // float4 chunk -> gapped

__device__ __forceinline__ float sigm(float x) { return 1.0f / (1.0f + __expf(-x)); }
__device__ __forceinline__ float tanh_fast(float x) { return 1.0f - 2.0f / (1.0f + __expf(2.0f * x)); }

#define RED4(v) { v += __shfl_xor(v, 1); v += __shfl_xor(v, 2); }

// Persistent GRU autoencoder, K-split-by-4 layout.
// grid = 512 WGs (1 batch row each, 2 WGs/CU), block = 512 (16 waves/CU = 4/SIMD).
// Thread (j,kq)=(tid>>2,tid&3) owns QUARTER kq of W_hh rows {j,128+j,256+j}
// = 24 float4 = 96 VGPRs. Total live ~125 <= 128: rounds 4+9 proved the
// allocator caps arch VGPRs at 128 regardless of waves_per_eu attributes
// (weights overflowed to AGPR/scratch: 45MB/dispatch of spill WRITE_SIZE,
// ~600 VALU inst/thread/step vs ~250 in source). Fit 128 -> no spill, and
// 2x occupancy. Partial dots combine via 2 shfl_xor rounds within lane quads.
__global__ __launch_bounds__(512)
__attribute__((amdgpu_waves_per_eu(4, 4)))
void gru_ae_kernel(
    const float* __restrict__ x,
    const float* __restrict__ eWih, const float* __restrict__ eWhh,
    const float* __restrict__ ebih, const float* __restrict__ ebhh,
    const float* __restrict__ efcW, const float* __restrict__ efcb,
    const float* __restrict__ dfcW, const float* __restrict__ dfcb,
    const float* __restrict__ dWih, const float* __restrict__ dWhh,
    const float* __restrict__ dbih, const float* __restrict__ dbhh,
    const float* __restrict__ oW, const float* __restrict__ ob,
    float* __restrict__ out)
{
    __shared__ __align__(16) float henc[2][HP4];   // ping-pong encoder h (gapped)
    __shared__ __align__(16) float hs[32][HP4];    // decoder 32-step h history (gapped)
    __shared__ __align__(16) float hdi[HP4];       // decoder input-hidden (gapped)
    __shared__ float zl[Ln];                       // latent z

    const int tid = threadIdx.x;
    const int j   = tid >> 2;       // hidden index 0..127
    const int kq  = tid & 3;        // K-quarter 0..3
    const int b   = blockIdx.x;     // one batch row per WG
    const int koff = kq * 32;       // global float offset of quarter
    const int klds = kq * QP;       // gapped LDS offset of quarter

    // ---- encoder W_hh quarter-rows into registers (96 VGPRs) ----
    float4 wr[8], wz[8], wn[8];
    {
        const float4* p0 = (const float4*)(eWhh + (size_t)j * Hd + koff);
        const float4* p1 = (const float4*)(eWhh + (size_t)(Hd + j) * Hd + koff);
        const float4* p2 = (const float4*)(eWhh + (size_t)(2 * Hd + j) * Hd + koff);
#pragma unroll
        for (int k = 0; k < 8; ++k) { wr[k] = p0[k]; wz[k] = p1[k]; wn[k] = p2[k]; }
    }
    // x-projection split across the quad: kq0 d={0,1}, kq1 d={2,3}, kq2 d={4}, kq3 none
    const int d0s = (kq == 1) ? 2 : (kq == 2) ? 4 : 0;
    const int inc = (kq < 2) ? 1 : 0;
    const float m0 = (kq < 3) ? 1.f : 0.f, m1 = (kq < 2) ? 1.f : 0.f;
    float wxr0 = m0 * eWih[(size_t)j * Dn + d0s];
    float wxr1 = m1 * eWih[(size_t)j * Dn + d0s + inc];
    float wxz0 = m0 * eWih[(size_t)(Hd + j) * Dn + d0s];
    float wxz1 = m1 * eWih[(size_t)(Hd + j) * Dn + d0s + inc];
    float wxn0 = m0 * eWih[(size_t)(2 * Hd + j) * Dn + d0s];
    float wxn1 = m1 * eWih[(size_t)(2 * Hd + j) * Dn + d0s + inc];

    float bR = ebih[j] + ebhh[j];
    float bZ = ebih[Hd + j] + ebhh[Hd + j];
    float bihn = ebih[2 * Hd + j];
    float bhhn = ebhh[2 * Hd + j];

    if (tid < Hd) { henc[0][GF(tid)] = 0.f; henc[1][GF(tid)] = 0.f; }
    __syncthreads();

    float h_self = 0.f;
    int p = 0;
    const float* xrow = x + (size_t)b * Tn * Dn;
    float xc0 = xrow[d0s], xc1 = xrow[d0s + inc];

    // ================= encoder: 1024 steps, 1 barrier/step =================
#pragma unroll 1
    for (int t = 0; t < Tn; ++t) {
        // prefetch next step's x pair (lands during the 96-FMA block)
        const int off = ((t + 1 < Tn) ? (t + 1) : (Tn - 1)) * Dn;
        float nx0 = xrow[off + d0s], nx1 = xrow[off + d0s + inc];

        const float4* hv = (const float4*)&henc[p][klds];
        float ar = 0.f, az = 0.f, nh = 0.f;
#pragma unroll
        for (int k = 0; k < 8; ++k) {
            float4 h4 = hv[k];
            ar = fmaf(wr[k].x, h4.x, ar); az = fmaf(wz[k].x, h4.x, az); nh = fmaf(wn[k].x, h4.x, nh);
            ar = fmaf(wr[k].y, h4.y, ar); az = fmaf(wz[k].y, h4.y, az); nh = fmaf(wn[k].y, h4.y, nh);
            ar = fmaf(wr[k].z, h4.z, ar); az = fmaf(wz[k].z, h4.z, az); nh = fmaf(wn[k].z, h4.z, nh);
            ar = fmaf(wr[k].w, h4.w, ar); az = fmaf(wz[k].w, h4.w, az); nh = fmaf(wn[k].w, h4.w, nh);
        }
        // x partials (r,z fold into the h-dot; n's x-part reduces separately)
        ar = fmaf(wxr0, xc0, fmaf(wxr1, xc1, ar));
        az = fmaf(wxz0, xc0, fmaf(wxz1, xc1, az));
        float nx = fmaf(wxn0, xc0, wxn1 * xc1);
        RED4(ar); RED4(az); RED4(nh); RED4(nx);
        float r  = sigm(ar + bR);
        float zg = sigm(az + bZ);
        float n  = tanh_fast(nx + bihn + r * (nh + bhhn));
        float hnew = fmaf(zg, h_self - n, n);   // (1-z)*n + z*h
        h_self = hnew;
        if (!kq) henc[p ^ 1][GF(j)] = hnew;
        xc0 = nx0; xc1 = nx1;
        __syncthreads();
        p ^= 1;
    }

    // ================= latent z =================
    if (tid < Ln) {
        const float4* wp = (const float4*)(efcW + (size_t)tid * Hd);
        float acc = efcb[tid];
#pragma unroll
        for (int q = 0; q < 32; ++q) {
            float4 w4 = wp[q];
            float4 h4 = *(const float4*)&henc[p][CF(q)];
            acc = fmaf(w4.x, h4.x, fmaf(w4.y, h4.y, fmaf(w4.z, h4.z, fmaf(w4.w, h4.w, acc))));
        }
        out[(size_t)Bn * Tn * Dn + (size_t)b * Ln + tid] = acc;
        zl[tid] = acc;
    }
    __syncthreads();

    // ================= h_dec_in = z @ dec_fc_W.T + dec_fc_b =================
    if (tid < Hd) {
        const float4* wp = (const float4*)(dfcW + (size_t)tid * Ln);
        float acc = dfcb[tid];
#pragma unroll
        for (int l = 0; l < 4; ++l) {
            float4 w4 = wp[l];
            acc = fmaf(w4.x, zl[4 * l + 0], acc);
            acc = fmaf(w4.y, zl[4 * l + 1], acc);
            acc = fmaf(w4.z, zl[4 * l + 2], acc);
            acc = fmaf(w4.w, zl[4 * l + 3], acc);
        }
        hdi[GF(tid)] = acc;
    }
    __syncthreads();

    // ================= xp_dec (constant over decoder steps) =================
    float xdr, xdz, xdn;
    {
        const float4* p0 = (const float4*)(dWih + (size_t)j * Hd + koff);
        const float4* p1 = (const float4*)(dWih + (size_t)(Hd + j) * Hd + koff);
        const float4* p2 = (const float4*)(dWih + (size_t)(2 * Hd + j) * Hd + koff);
#pragma unroll
        for (int k = 0; k < 8; ++k) { wr[k] = p0[k]; wz[k] = p1[k]; wn[k] = p2[k]; }
        const float4* hv = (const float4*)&hdi[klds];
        float a0 = 0.f, a1 = 0.f, a2 = 0.f;
#pragma unroll
        for (int k = 0; k < 8; ++k) {
            float4 h4 = hv[k];
            a0 = fmaf(wr[k].x, h4.x, a0); a1 = fmaf(wz[k].x, h4.x, a1); a2 = fmaf(wn[k].x, h4.x, a2);
            a0 = fmaf(wr[k].y, h4.y, a0); a1 = fmaf(wz[k].y, h4.y, a1); a2 = fmaf(wn[k].y, h4.y, a2);
            a0 = fmaf(wr[k].z, h4.z, a0); a1 = fmaf(wz[k].z, h4.z, a1); a2 = fmaf(wn[k].z, h4.z, a2);
            a0 = fmaf(wr[k].w, h4.w, a0); a1 = fmaf(wz[k].w, h4.w, a1); a2 = fmaf(wn[k].w, h4.w, a2);
        }
        RED4(a0); RED4(a1); RED4(a2);
        xdr = a0 + dbih[j] + dbhh[j];
        xdz = a1 + dbih[Hd + j] + dbhh[Hd + j];
        xdn = a2 + dbih[2 * Hd + j];
        bhhn = dbhh[2 * Hd + j];
    }

    // ---- decoder W_hh quarter-rows ----
    {
        const float4* p0 = (const float4*)(dWhh + (size_t)j * Hd + koff);
        const float4* p1 = (const float4*)(dWhh + (size_t)(Hd + j) * Hd + koff);
        const float4* p2 = (const float4*)(dWhh + (size_t)(2 * Hd + j) * Hd + koff);
#pragma unroll
        for (int k = 0; k < 8; ++k) { wr[k] = p0[k]; wz[k] = p1[k]; wn[k] = p2[k]; }
    }

    if (tid < Hd) hs[31][GF(tid)] = 0.f;   // "previous h" for decoder step 0
    h_self = 0.f;
    __syncthreads();

    // ================= decoder: 1024 steps in 32-step tiles =================
#pragma unroll 1
    for (int s0 = 0; s0 < Tn; s0 += 32) {
#pragma unroll 1
        for (int ss = 0; ss < 32; ++ss) {
            const int ip = (ss + 31) & 31;
            const float4* hv = (const float4*)&hs[ip][klds];
            float ar = 0.f, az = 0.f, nh = 0.f;
#pragma unroll
            for (int k = 0; k < 8; ++k) {
                float4 h4 = hv[k];
                ar = fmaf(wr[k].x, h4.x, ar); az = fmaf(wz[k].x, h4.x, az); nh = fmaf(wn[k].x, h4.x, nh);
                ar = fmaf(wr[k].y, h4.y, ar); az = fmaf(wz[k].y, h4.y, az); nh = fmaf(wn[k].y, h4.y, nh);
                ar = fmaf(wr[k].z, h4.z, ar); az = fmaf(wz[k].z, h4.z, az); nh = fmaf(wn[k].z, h4.z, nh);
                ar = fmaf(wr[k].w, h4.w, ar); az = fmaf(wz[k].w, h4.w, az); nh = fmaf(wn[k].w, h4.w, nh);
            }
            RED4(ar); RED4(az); RED4(nh);
            float r  = sigm(xdr + ar);
            float zg = sigm(xdz + az);
            float n  = tanh_fast(xdn + r * (nh + bhhn));
            float hnew = fmaf(zg, h_self - n, n);
            h_self = hnew;
            if (!kq) hs[ss][GF(j)] = hnew;
            __syncthreads();
        }

        // ---- bulk recon projection for steps s0..s0+31 (coalesced stores) ----
        if (tid < 160) {
            const int i = tid / 5, d = tid % 5;
            const float4* wrow = (const float4*)(oW + (size_t)d * Hd);
            float ac0 = ob[d], ac1 = 0.f;
#pragma unroll
            for (int q = 0; q < 32; q += 2) {
                const int qa = (q + i) & 31, qb = (q + 1 + i) & 31;
                float4 ha = *(const float4*)&hs[i][CF(qa)];
                float4 wa = wrow[qa];
                float4 hb = *(const float4*)&hs[i][CF(qb)];
                float4 wb = wrow[qb];
                ac0 = fmaf(wa.x, ha.x, fmaf(wa.y, ha.y, fmaf(wa.z, ha.z, fmaf(wa.w, ha.w, ac0))));
                ac1 = fmaf(wb.x, hb.x, fmaf(wb.y, hb.y, fmaf(wb.z, hb.z, fmaf(wb.w, hb.w, ac1))));
            }
            out[((size_t)b * Tn + s0 + i) * Dn + d] = ac0 + ac1;
        }
        __syncthreads();   // protect hs before next tile overwrites slots
    }
}

extern "C" void kernel_launch(void* const* d_in, const int* in_sizes, int n_in,
                              void* d_out, int out_size, void* d_ws, size_t ws_size,
                              hipStream_t stream) {
    const float* x    = (const float*)d_in[0];
    const float* eWih = (const float*)d_in[1];
    const float* eWhh = (const float*)d_in[2];
    const float* ebih = (const float*)d_in[3];
    const float* ebhh = (const float*)d_in[4];
    const float* efcW = (const float*)d_in[5];
    const float* efcb = (const float*)d_in[6];
    const float* dfcW = (const float*)d_in[7];
    const float* dfcb = (const float*)d_in[8];
    const float* dWih = (const float*)d_in[9];
    const float* dWhh = (const float*)d_in[10];
    const float* dbih = (const float*)d_in[11];
    const float* dbhh = (const float*)d_in[12];
    const float* oW   = (const float*)d_in[13];
    const float* ob   = (const float*)d_in[14];
    float* out = (float*)d_out;

    gru_ae_kernel<<<dim3(Bn), dim3(512), 0, stream>>>(
        x, eWih, eWhh, ebih, ebhh, efcW, efcb, dfcW, dfcb,
        dWih, dWhh, dbih, dbhh, oW, ob, out);
}